// Round 5
// baseline (400.065 us; speedup 1.0000x reference)
//
#include <hip/hip_runtime.h>
#include <hip/hip_bf16.h>
#include <cstdint>
#include <cstddef>

using bf16 = __hip_bfloat16;
typedef __attribute__((ext_vector_type(8))) __bf16 bf16x8;
typedef __attribute__((ext_vector_type(4))) float f32x4;

typedef const __attribute__((address_space(1))) void CGV;
typedef __attribute__((address_space(3))) void LDSV;

__device__ __forceinline__ void gload_lds16(const void* g, void* l) {
    // global side is per-lane addressed; LDS dest is wave-uniform base + lane*16.
    __builtin_amdgcn_global_load_lds((CGV*)g, (LDSV*)l, 16, 0, 0);
}

__device__ __forceinline__ float bits2f(unsigned short u) {
    return __uint_as_float(((unsigned)u) << 16);
}
__device__ __forceinline__ unsigned short f2bits(float f) {
    return __builtin_bit_cast(unsigned short, __float2bfloat16(f));
}

// ---------------------------------------------------------------------------
// prep: one launch doing  [0,16384): cast x fp32->bf16
//                         [16384,19456): transpose+cast Wq/Wk/Wv -> (N,K) bf16
//                         [19456,19472): G = RF @ RF^T
__global__ __launch_bounds__(256) void prep_kernel(
    const float4* __restrict__ x4, ushort4* __restrict__ Xb4,
    const float* __restrict__ Wq, const float* __restrict__ Wk,
    const float* __restrict__ Wv, bf16* __restrict__ Wt3,
    const float* __restrict__ RF, float* __restrict__ G)
{
    const int bi = blockIdx.x;
    const int t = threadIdx.x;
    if (bi < 16384) {
        int i = bi * 256 + t;
        float4 f = x4[i];
        ushort4 u;
        u.x = f2bits(f.x); u.y = f2bits(f.y); u.z = f2bits(f.z); u.w = f2bits(f.w);
        Xb4[i] = u;
    } else if (bi < 19456) {
        int rem = bi - 16384;
        int z = rem >> 10;              // 0..2
        int r2 = rem & 1023;
        int bx = r2 & 31, by = r2 >> 5;
        const float* W = (z == 0) ? Wq : (z == 1) ? Wk : Wv;
        bf16* O = Wt3 + (size_t)z * (1024 * 1024);
        __shared__ float tile[32][33];
        int tx = t & 31, ty = t >> 5;   // 32 x 8
        int xg = bx * 32 + tx;          // n
        int y0 = by * 32;               // k base
        for (int i = ty; i < 32; i += 8)
            tile[i][tx] = W[(size_t)(y0 + i) * 1024 + xg];
        __syncthreads();
        int xo = by * 32 + tx;          // k
        int yo = bx * 32;               // n base
        for (int i = ty; i < 32; i += 8)
            O[(size_t)(yo + i) * 1024 + xo] = __float2bfloat16(tile[tx][i]);
    } else {
        int o = (bi - 19456) * 256 + t; // 0..4095
        int i = o >> 6, j = o & 63;
        const float4* a = (const float4*)(RF + (size_t)i * 256);
        const float4* b = (const float4*)(RF + (size_t)j * 256);
        float s = 0.f;
        for (int f = 0; f < 64; f++) {
            float4 xx = a[f], yy = b[f];
            s += xx.x * yy.x + xx.y * yy.y + xx.z * yy.z + xx.w * yy.w;
        }
        G[o] = s;
    }
}

// ---------------------------------------------------------------------------
// Q projection GEMM: Qp = phi(Xb @ Wq + bq), 16384x1024x1024, row-major out.
// XCD-swizzled blocks, LDS XOR-swizzle (0 bank conflicts, verified R2).
__global__ __launch_bounds__(256, 2) void gemm_q(
    const bf16* __restrict__ X, const bf16* __restrict__ Wt3,
    const float* __restrict__ bq, bf16* __restrict__ Qo)
{
    __shared__ bf16 As[128 * 64];
    __shared__ bf16 Bs[128 * 64];
    const int lid = blockIdx.x + (blockIdx.y << 3);
    const int xcd = lid & 7, seq = lid >> 3;
    const int m0 = (xcd * 16 + (seq >> 3)) * 128;
    const int n0 = (seq & 7) * 128;
    const int tid = threadIdx.x;
    const int w = tid >> 6, lane = tid & 63;
    const int lr = lane >> 3, lc = lane & 7;
    const int sc = lc ^ lr;

    const bf16* ag = X   + (size_t)(m0 + w * 32 + lr) * 1024 + sc * 8;
    const bf16* bg = Wt3 + (size_t)(n0 + w * 32 + lr) * 1024 + sc * 8;
    bf16* al = As + (w * 32) * 64;
    bf16* bl = Bs + (w * 32) * 64;

    f32x4 acc[4][4];
#pragma unroll
    for (int i = 0; i < 4; i++)
#pragma unroll
        for (int j = 0; j < 4; j++) acc[i][j] = (f32x4){0.f, 0.f, 0.f, 0.f};

    const int lm = lane & 15, quad = lane >> 4;
    const int x0 = (quad ^ (lm & 7)) * 8;
    const int x1 = ((quad + 4) ^ (lm & 7)) * 8;
    const bf16* Ab = As + ((w >> 1) * 64 + lm) * 64;
    const bf16* Bb = Bs + ((w & 1) * 64 + lm) * 64;

    for (int k0 = 0; k0 < 1024; k0 += 64) {
#pragma unroll
        for (int j = 0; j < 4; j++) {
            gload_lds16(ag + (size_t)j * 8 * 1024 + k0, al + j * 8 * 64);
            gload_lds16(bg + (size_t)j * 8 * 1024 + k0, bl + j * 8 * 64);
        }
        __syncthreads();
#pragma unroll
        for (int kk = 0; kk < 2; kk++) {
            const int xo = kk ? x1 : x0;
            bf16x8 a[4], b[4];
#pragma unroll
            for (int i = 0; i < 4; i++) a[i] = *(const bf16x8*)(Ab + i * 16 * 64 + xo);
#pragma unroll
            for (int i = 0; i < 4; i++) b[i] = *(const bf16x8*)(Bb + i * 16 * 64 + xo);
#pragma unroll
            for (int mi = 0; mi < 4; mi++)
#pragma unroll
                for (int ni = 0; ni < 4; ni++)
                    acc[mi][ni] = __builtin_amdgcn_mfma_f32_16x16x32_bf16(
                        a[mi], b[ni], acc[mi][ni], 0, 0, 0);
        }
        __syncthreads();
    }

    const int wr = (w >> 1) * 64, wc = (w & 1) * 64;
#pragma unroll
    for (int ni = 0; ni < 4; ni++) {
        int col = n0 + wc + ni * 16 + lm;
        float bs = bq[col];
#pragma unroll
        for (int mi = 0; mi < 4; mi++) {
            int row0 = m0 + wr + mi * 16 + quad * 4;
#pragma unroll
            for (int r = 0; r < 4; r++) {
                float v = acc[mi][ni][r] + bs;
                v = (v > 0.f) ? (v + 1.f) : __expf(v);
                Qo[(size_t)(row0 + r) * 1024 + col] = __float2bfloat16(v);
            }
        }
    }
}

// ---------------------------------------------------------------------------
// Fused K,V projection + per-tile S contribution. One block = 128x128 tile of
// BOTH phi(K) and V (A-tile staged once, shared). Epilogue: transpose both
// tiles into LDS (b64-packed from acc regs), S-MFMA per head (64x64x128),
// write S-partials. K/V never touch HBM; s_kernel eliminated.
// Spart2[(b*16+h)*32 + mt][64][64] fp32, mt = (m0&4095)>>7.
__global__ __launch_bounds__(256, 2) void gemm_kvs(
    const bf16* __restrict__ X, const bf16* __restrict__ Wt3,
    const float* __restrict__ bk, const float* __restrict__ bv,
    float* __restrict__ Spart2)
{
    __shared__ bf16 smem[24576];   // 48 KB: A[0:8192] Bk[8192:16384] Bv[16384:24576]
    bf16* As  = smem;
    bf16* Bks = smem + 8192;
    bf16* Bvs = smem + 16384;

    const int lid = blockIdx.x + (blockIdx.y << 3);
    const int xcd = lid & 7, seq = lid >> 3;
    const int m0 = (xcd * 16 + (seq >> 3)) * 128;
    const int n0 = (seq & 7) * 128;
    const int tid = threadIdx.x;
    const int w = tid >> 6, lane = tid & 63;
    const int lr = lane >> 3, lc = lane & 7;
    const int sc = lc ^ lr;

    const bf16* ag  = X + (size_t)(m0 + w * 32 + lr) * 1024 + sc * 8;
    const bf16* bgk = Wt3 + (size_t)(1 << 20) + (size_t)(n0 + w * 32 + lr) * 1024 + sc * 8;
    const bf16* bgv = Wt3 + (size_t)(2 << 20) + (size_t)(n0 + w * 32 + lr) * 1024 + sc * 8;
    bf16* al  = As  + (w * 32) * 64;
    bf16* blk = Bks + (w * 32) * 64;
    bf16* blv = Bvs + (w * 32) * 64;

    f32x4 acck[4][4], accv[4][4];
#pragma unroll
    for (int i = 0; i < 4; i++)
#pragma unroll
        for (int j = 0; j < 4; j++) {
            acck[i][j] = (f32x4){0.f, 0.f, 0.f, 0.f};
            accv[i][j] = (f32x4){0.f, 0.f, 0.f, 0.f};
        }

    const int lm = lane & 15, quad = lane >> 4;
    const int x0 = (quad ^ (lm & 7)) * 8;
    const int x1 = ((quad + 4) ^ (lm & 7)) * 8;
    const bf16* Ab  = As  + ((w >> 1) * 64 + lm) * 64;
    const bf16* Bbk = Bks + ((w & 1) * 64 + lm) * 64;
    const bf16* Bbv = Bvs + ((w & 1) * 64 + lm) * 64;

    for (int k0 = 0; k0 < 1024; k0 += 64) {
#pragma unroll
        for (int j = 0; j < 4; j++) {
            gload_lds16(ag  + (size_t)j * 8 * 1024 + k0, al  + j * 8 * 64);
            gload_lds16(bgk + (size_t)j * 8 * 1024 + k0, blk + j * 8 * 64);
            gload_lds16(bgv + (size_t)j * 8 * 1024 + k0, blv + j * 8 * 64);
        }
        __syncthreads();
#pragma unroll
        for (int kk = 0; kk < 2; kk++) {
            const int xo = kk ? x1 : x0;
            bf16x8 a[4], bb[4];
#pragma unroll
            for (int i = 0; i < 4; i++) a[i] = *(const bf16x8*)(Ab + i * 16 * 64 + xo);
#pragma unroll
            for (int i = 0; i < 4; i++) bb[i] = *(const bf16x8*)(Bbk + i * 16 * 64 + xo);
#pragma unroll
            for (int mi = 0; mi < 4; mi++)
#pragma unroll
                for (int ni = 0; ni < 4; ni++)
                    acck[mi][ni] = __builtin_amdgcn_mfma_f32_16x16x32_bf16(
                        a[mi], bb[ni], acck[mi][ni], 0, 0, 0);
#pragma unroll
            for (int i = 0; i < 4; i++) bb[i] = *(const bf16x8*)(Bbv + i * 16 * 64 + xo);
#pragma unroll
            for (int mi = 0; mi < 4; mi++)
#pragma unroll
                for (int ni = 0; ni < 4; ni++)
                    accv[mi][ni] = __builtin_amdgcn_mfma_f32_16x16x32_bf16(
                        a[mi], bb[ni], accv[mi][ni], 0, 0, 0);
        }
        __syncthreads();
    }

    // ---- epilogue: per head, transpose k'/v tiles into LDS, S-MFMA, store ----
    // KT at smem[0], VT at smem[8704]; layout [head-local col][row] pad 136.
    const int b = m0 >> 12, mt = (m0 & 4095) >> 7;
    const int h0 = n0 >> 6;
    const int wr = (w >> 1) * 64;
    const int myh = w & 1;             // which head this wave's cols belong to

#pragma unroll
    for (int ih = 0; ih < 2; ih++) {
        __syncthreads();               // LDS free for reuse / prev head's reads done
        if (myh == ih) {
#pragma unroll
            for (int ni = 0; ni < 4; ni++) {
                int lc2 = ni * 16 + lm;                 // head-local col 0..63
                int col = n0 + myh * 64 + lc2;          // global col
                float bsk = bk[col], bsv = bv[col];
#pragma unroll
                for (int mi = 0; mi < 4; mi++) {
                    int row = wr + mi * 16 + quad * 4;  // local row, mult of 4
                    ushort4 kp, vp;
                    {
                        float v0 = acck[mi][ni][0] + bsk; v0 = (v0 > 0.f) ? (v0 + 1.f) : __expf(v0);
                        float v1 = acck[mi][ni][1] + bsk; v1 = (v1 > 0.f) ? (v1 + 1.f) : __expf(v1);
                        float v2 = acck[mi][ni][2] + bsk; v2 = (v2 > 0.f) ? (v2 + 1.f) : __expf(v2);
                        float v3 = acck[mi][ni][3] + bsk; v3 = (v3 > 0.f) ? (v3 + 1.f) : __expf(v3);
                        kp.x = f2bits(v0); kp.y = f2bits(v1); kp.z = f2bits(v2); kp.w = f2bits(v3);
                    }
                    {
                        float v0 = accv[mi][ni][0] + bsv;
                        float v1 = accv[mi][ni][1] + bsv;
                        float v2 = accv[mi][ni][2] + bsv;
                        float v3 = accv[mi][ni][3] + bsv;
                        vp.x = f2bits(v0); vp.y = f2bits(v1); vp.z = f2bits(v2); vp.w = f2bits(v3);
                    }
                    *(ushort4*)&smem[lc2 * 136 + row]        = kp;   // KT[e][n]
                    *(ushort4*)&smem[8704 + lc2 * 136 + row] = vp;   // VT[d][n]
                }
            }
        }
        __syncthreads();
        // S = K'^T @ V for this head: 64x64, k=128. Wave w owns e-tile w.
        f32x4 sacc[4];
#pragma unroll
        for (int dt = 0; dt < 4; dt++) sacc[dt] = (f32x4){0.f, 0.f, 0.f, 0.f};
#pragma unroll
        for (int ks = 0; ks < 4; ks++) {
            bf16x8 af = *(const bf16x8*)&smem[(w * 16 + lm) * 136 + ks * 32 + quad * 8];
#pragma unroll
            for (int dt = 0; dt < 4; dt++) {
                bf16x8 bf = *(const bf16x8*)&smem[8704 + (dt * 16 + lm) * 136 + ks * 32 + quad * 8];
                sacc[dt] = __builtin_amdgcn_mfma_f32_16x16x32_bf16(af, bf, sacc[dt], 0, 0, 0);
            }
        }
        float* sb = Spart2 + (((size_t)(b * 16 + h0 + ih) * 32 + mt) << 12);
#pragma unroll
        for (int dt = 0; dt < 4; dt++)
#pragma unroll
            for (int r = 0; r < 4; r++)
                sb[(w * 16 + quad * 4 + r) * 64 + dt * 16 + lm] = sacc[dt][r];
    }
}

// ---------------------------------------------------------------------------
// reduce the 32 m-tile partials: S[bh][4096] = sum_mt Spart2[bh*32+mt][4096]
__global__ __launch_bounds__(256) void reduce_s2(const float* __restrict__ Spart2,
                                                 float* __restrict__ S)
{
    const int bh = blockIdx.x, t = threadIdx.x;
    const float* base = Spart2 + ((size_t)bh << 17);   // 32*4096
    for (int j = 0; j < 16; j++) {
        int i = j * 256 + t;
        float s = 0.f;
#pragma unroll
        for (int mtl = 0; mtl < 32; mtl++) s += base[(mtl << 12) + i];
        S[((size_t)bh << 12) + i] = s;
    }
}

// ---------------------------------------------------------------------------
// fold2: (M = G@S) + fold-into-Wo.
// grid 256 = (b, h, cblk): Wo2t[b][c][h*64+e] = sum_d (G@S[b,h])[e][d] * Wo[h*64+d][c]
__global__ __launch_bounds__(256) void fold2_kernel(const float* __restrict__ S,
                                                    const float* __restrict__ G,
                                                    const float* __restrict__ Wo,
                                                    bf16* __restrict__ Wo2t)
{
    __shared__ float Sl[4096];   // S[e*64+d]
    __shared__ float Ml[4096];   // transposed M: Ml[d*64+e]
    const int xb = blockIdx.x;
    const int b = xb >> 6, h = (xb >> 2) & 15, cb = xb & 3;
    const int bh = b * 16 + h;
    const int t = threadIdx.x;

    for (int i = t; i < 4096; i += 256) Sl[i] = S[((size_t)bh << 12) + i];
    __syncthreads();

    {
        const int e = t >> 2, dblk = (t & 3) * 16;
        float acc[16];
#pragma unroll
        for (int j = 0; j < 16; j++) acc[j] = 0.f;
        for (int ep = 0; ep < 64; ep++) {
            float g = G[e * 64 + ep];
#pragma unroll
            for (int j = 0; j < 16; j++) acc[j] += g * Sl[ep * 64 + dblk + j];
        }
        __syncthreads();
#pragma unroll
        for (int j = 0; j < 16; j++) Ml[(dblk + j) * 64 + e] = acc[j];
    }
    __syncthreads();

    const int c = cb * 256 + t;
    float acc[64];
#pragma unroll
    for (int e = 0; e < 64; e++) acc[e] = 0.f;
    for (int d = 0; d < 64; d++) {
        float wo = Wo[(size_t)(h * 64 + d) * 1024 + c];
#pragma unroll
        for (int e = 0; e < 64; e++) acc[e] += Ml[d * 64 + e] * wo;
    }
    unsigned* outp = (unsigned*)(Wo2t + ((size_t)b * 1024 + c) * 1024 + h * 64);
#pragma unroll
    for (int e = 0; e < 64; e += 2) {
        unsigned lo = f2bits(acc[e]);
        unsigned hi = f2bits(acc[e + 1]);
        outp[e >> 1] = lo | (hi << 16);
    }
}

// ---------------------------------------------------------------------------
// Final GEMM: out = phi(q) @ Wo'_b + bo, fp32 output. grid (8,128).
__global__ __launch_bounds__(256, 2) void gemm_out(
    const bf16* __restrict__ Qp, const bf16* __restrict__ Wo2t,
    const float* __restrict__ bo, float* __restrict__ Out)
{
    __shared__ bf16 As[128 * 64];
    __shared__ bf16 Bs[128 * 64];
    const int lid = blockIdx.x + (blockIdx.y << 3);
    const int xcd = lid & 7, seq = lid >> 3;
    const int m0 = (xcd * 16 + (seq >> 3)) * 128;
    const int n0 = (seq & 7) * 128;
    const int tid = threadIdx.x;
    const int w = tid >> 6, lane = tid & 63;
    const int lr = lane >> 3, lc = lane & 7;
    const int sc = lc ^ lr;
    const bf16* Wt = Wo2t + (size_t)(m0 >> 12) * (1024 * 1024);   // per-batch weights

    const bf16* ag = Qp + (size_t)(m0 + w * 32 + lr) * 1024 + sc * 8;
    const bf16* bg = Wt + (size_t)(n0 + w * 32 + lr) * 1024 + sc * 8;
    bf16* al = As + (w * 32) * 64;
    bf16* bl = Bs + (w * 32) * 64;

    f32x4 acc[4][4];
#pragma unroll
    for (int i = 0; i < 4; i++)
#pragma unroll
        for (int j = 0; j < 4; j++) acc[i][j] = (f32x4){0.f, 0.f, 0.f, 0.f};

    const int lm = lane & 15, quad = lane >> 4;
    const int x0 = (quad ^ (lm & 7)) * 8;
    const int x1 = ((quad + 4) ^ (lm & 7)) * 8;
    const bf16* Ab = As + ((w >> 1) * 64 + lm) * 64;
    const bf16* Bb = Bs + ((w & 1) * 64 + lm) * 64;

    for (int k0 = 0; k0 < 1024; k0 += 64) {
#pragma unroll
        for (int j = 0; j < 4; j++) {
            gload_lds16(ag + (size_t)j * 8 * 1024 + k0, al + j * 8 * 64);
            gload_lds16(bg + (size_t)j * 8 * 1024 + k0, bl + j * 8 * 64);
        }
        __syncthreads();
#pragma unroll
        for (int kk = 0; kk < 2; kk++) {
            const int xo = kk ? x1 : x0;
            bf16x8 a[4], b[4];
#pragma unroll
            for (int i = 0; i < 4; i++) a[i] = *(const bf16x8*)(Ab + i * 16 * 64 + xo);
#pragma unroll
            for (int i = 0; i < 4; i++) b[i] = *(const bf16x8*)(Bb + i * 16 * 64 + xo);
#pragma unroll
            for (int mi = 0; mi < 4; mi++)
#pragma unroll
                for (int ni = 0; ni < 4; ni++)
                    acc[mi][ni] = __builtin_amdgcn_mfma_f32_16x16x32_bf16(
                        a[mi], b[ni], acc[mi][ni], 0, 0, 0);
        }
        __syncthreads();
    }

    const int wr = (w >> 1) * 64, wc = (w & 1) * 64;
#pragma unroll
    for (int ni = 0; ni < 4; ni++) {
        int col = n0 + wc + ni * 16 + lm;
        float bs = bo[col];
#pragma unroll
        for (int mi = 0; mi < 4; mi++) {
            int row0 = m0 + wr + mi * 16 + quad * 4;
#pragma unroll
            for (int r = 0; r < 4; r++)
                Out[(size_t)(row0 + r) * 1024 + col] = acc[mi][ni][r] + bs;
        }
    }
}

// ---------------------------------------------------------------------------
extern "C" void kernel_launch(void* const* d_in, const int* in_sizes, int n_in,
                              void* d_out, int out_size, void* d_ws, size_t ws_size,
                              hipStream_t stream) {
    const float* x  = (const float*)d_in[0];
    const float* Wq = (const float*)d_in[1];
    const float* bq = (const float*)d_in[2];
    const float* Wk = (const float*)d_in[3];
    const float* bk = (const float*)d_in[4];
    const float* Wv = (const float*)d_in[5];
    const float* bv = (const float*)d_in[6];
    const float* Wo = (const float*)d_in[7];
    const float* bo = (const float*)d_in[8];
    const float* RF = (const float*)d_in[9];
    float* out = (float*)d_out;

    char* ws = (char*)d_ws;
    bf16*  Xb     = (bf16*) (ws);                           // 32 MB
    bf16*  Qp     = (bf16*) (ws + ((size_t)32  << 20));     // 32 MB row-major
    bf16*  Wt3    = (bf16*) (ws + ((size_t)64  << 20));     // 6 MB (Wq^T,Wk^T,Wv^T)
    bf16*  Wo2t   = (bf16*) (ws + ((size_t)70  << 20));     // 8 MB
    float* Spart2 = (float*)(ws + ((size_t)80  << 20));     // 32 MB (64 bh x 32 mt x 4096)
    float* S      = (float*)(ws + ((size_t)112 << 20));     // 1 MB
    float* G      = (float*)(ws + ((size_t)113 << 20));     // 16 KB

    prep_kernel<<<19472, 256, 0, stream>>>((const float4*)x, (ushort4*)Xb,
                                           Wq, Wk, Wv, Wt3, RF, G);
    gemm_q<<<dim3(8, 128), 256, 0, stream>>>(Xb, Wt3, bq, Qp);
    gemm_kvs<<<dim3(8, 128), 256, 0, stream>>>(Xb, Wt3, bk, bv, Spart2);
    reduce_s2<<<64, 256, 0, stream>>>(Spart2, S);
    fold2_kernel<<<256, 256, 0, stream>>>(S, G, Wo, Wo2t);
    gemm_out<<<dim3(8, 128), 256, 0, stream>>>(Qp, Wo2t, bo, out);
}